// Round 2
// baseline (169.385 us; speedup 1.0000x reference)
//
#include <hip/hip_runtime.h>
#include <math.h>

#define NQ 12
#define DIM 4096
#define NLAYER 4
#define NT 512
#define EPT 8  // complex amplitudes per thread

// LDS element-index swizzle: XOR bits 6..8 into 0..2.
// Verified conflict-free(-equivalent) for all four access patterns used below.
__device__ __forceinline__ int swz(int i) { return i ^ ((i >> 6) & 7); }

__device__ __forceinline__ float block_reduce_sum(float v, float* red) {
  const int tid = threadIdx.x;
#pragma unroll
  for (int off = 32; off > 0; off >>= 1) v += __shfl_down(v, off, 64);
  if ((tid & 63) == 0) red[tid >> 6] = v;
  __syncthreads();
  if (tid == 0) {
    float s = 0.f;
#pragma unroll
    for (int i = 0; i < NT / 64; ++i) s += red[i];
    red[0] = s;
  }
  __syncthreads();
  float r = red[0];
  __syncthreads();
  return r;
}

__device__ __forceinline__ void apply_pair(float2& a0, float2& a1,
    const float2 u00, const float2 u01, const float2 u10, const float2 u11) {
  float2 n0, n1;
  n0.x = u00.x * a0.x - u00.y * a0.y + u01.x * a1.x - u01.y * a1.y;
  n0.y = u00.x * a0.y + u00.y * a0.x + u01.x * a1.y + u01.y * a1.x;
  n1.x = u10.x * a0.x - u10.y * a0.y + u11.x * a1.x - u11.y * a1.y;
  n1.y = u10.x * a0.y + u10.y * a0.x + u11.x * a1.y + u11.y * a1.x;
  a0 = n0; a1 = n1;
}

__global__ __launch_bounds__(NT, 4) void qsim_kernel(
    const float* __restrict__ x, const float* __restrict__ w,
    float* __restrict__ out) {
  __shared__ float2 st[DIM];               // 32 KB statevector (swizzled)
  __shared__ float2 gmat[NLAYER * NQ * 4];
  __shared__ float red[NT / 64];

  const int tid = threadIdx.x;
  const int lane = tid & 63;
  const int wave = tid >> 6;
  const long b = blockIdx.x;

  // --- gate matrices (48 gates, one thread each) ---
  if (tid < NLAYER * NQ) {
    const float* wp = w + tid * 3;
    float phi = wp[0], th = wp[1], om = wp[2];
    float sn, c, sa, ca, sb, cb;
    sincosf(0.5f * th, &sn, &c);
    sincosf(0.5f * (phi + om), &sa, &ca);
    sincosf(0.5f * (phi - om), &sb, &cb);
    float2* g = &gmat[tid * 4];
    g[0] = make_float2(ca * c, -sa * c);    // U00
    g[1] = make_float2(-cb * sn, -sb * sn); // U01
    g[2] = make_float2(cb * sn, -sb * sn);  // U10
    g[3] = make_float2(ca * c, sa * c);     // U11
  }

  // --- load 8 consecutive x, norm, amplitude-encode into registers ---
  const float4* xr = (const float4*)(x + b * (long)DIM) + tid * 2;
  float4 xv0 = xr[0], xv1 = xr[1];
  float xv[EPT] = {xv0.x, xv0.y, xv0.z, xv0.w, xv1.x, xv1.y, xv1.z, xv1.w};
  float ss = 0.f;
#pragma unroll
  for (int e = 0; e < EPT; ++e) ss += xv[e] * xv[e];
  float nrm = sqrtf(block_reduce_sum(ss, red));  // barriers also cover gmat init
  bool ok = nrm > 1e-10f;
  float inv = ok ? 1.0f / nrm : 0.f;

  float2 s[EPT];
#pragma unroll
  for (int e = 0; e < EPT; ++e)
    s[e] = make_float2(ok ? xv[e] * inv : 0.015625f, 0.f);

  // Layout X: element (tid,e) holds logical index tid*8+e
  //   -> bits 0..2 = e (reg), 3..8 = lane, 9..11 = wave
  // Layout Y: element (tid,e) holds logical (e<<9)|(lane<<3)|wave
  //   -> bits 9..11 = e (reg)
  for (int L = 0; L < NLAYER; ++L) {
    const float2* G = &gmat[L * NQ * 4];

    // --- X-phase: lane gates q=3..8 (bit p=8..3, lane bit LB=8-q) ---
#pragma unroll
    for (int q = 3; q <= 8; ++q) {
      const int LB = 8 - q;
      const float2 u00 = G[q * 4 + 0], u01 = G[q * 4 + 1];
      const float2 u10 = G[q * 4 + 2], u11 = G[q * 4 + 3];
      float2 pv[EPT];
#pragma unroll
      for (int e = 0; e < EPT; ++e) {
        pv[e].x = __shfl_xor(s[e].x, 1 << LB, 64);
        pv[e].y = __shfl_xor(s[e].y, 1 << LB, 64);
      }
      const int role = (lane >> LB) & 1;
      const float2 cs = role ? u11 : u00;  // coeff on self
      const float2 cp = role ? u10 : u01;  // coeff on partner
#pragma unroll
      for (int e = 0; e < EPT; ++e) {
        float2 n;
        n.x = cs.x * s[e].x - cs.y * s[e].y + cp.x * pv[e].x - cp.y * pv[e].y;
        n.y = cs.x * s[e].y + cs.y * s[e].x + cp.x * pv[e].y + cp.y * pv[e].x;
        s[e] = n;
      }
    }
    // --- X-phase: register gates q=9,10,11 (bit p = 11-q = e-bit B) ---
#pragma unroll
    for (int q = 9; q <= 11; ++q) {
      const int B = 11 - q;
      const float2 u00 = G[q * 4 + 0], u01 = G[q * 4 + 1];
      const float2 u10 = G[q * 4 + 2], u11 = G[q * 4 + 3];
#pragma unroll
      for (int pe = 0; pe < 4; ++pe) {
        int e0 = ((pe >> B) << (B + 1)) | (pe & ((1 << B) - 1));
        apply_pair(s[e0], s[e0 | (1 << B)], u00, u01, u10, u11);
      }
    }

    // --- relayout X -> Y ---
    __syncthreads();
#pragma unroll
    for (int e = 0; e < EPT; ++e) st[swz(tid * 8 + e)] = s[e];
    __syncthreads();
#pragma unroll
    for (int e = 0; e < EPT; ++e)
      s[e] = st[swz((e << 9) | (lane << 3) | wave)];

    // --- Y-phase: register gates q=0,1,2 (bit p=11-q -> e-bit B=2-q) ---
#pragma unroll
    for (int q = 0; q <= 2; ++q) {
      const int B = 2 - q;
      const float2 u00 = G[q * 4 + 0], u01 = G[q * 4 + 1];
      const float2 u10 = G[q * 4 + 2], u11 = G[q * 4 + 3];
#pragma unroll
      for (int pe = 0; pe < 4; ++pe) {
        int e0 = ((pe >> B) << (B + 1)) | (pe & ((1 << B) - 1));
        apply_pair(s[e0], s[e0 | (1 << B)], u00, u01, u10, u11);
      }
    }

    // --- relayout Y -> X with CNOT-cascade permutation fused ---
    __syncthreads();
#pragma unroll
    for (int e = 0; e < EPT; ++e)
      st[swz((e << 9) | (lane << 3) | wave)] = s[e];
    __syncthreads();
#pragma unroll
    for (int e = 0; e < EPT; ++e) {
      int y = tid * 8 + e;
      int z = y;
      z ^= z >> 1; z ^= z >> 2; z ^= z >> 4; z ^= z >> 8;
      s[e] = st[swz(z & (DIM - 1))];
    }
  }

  // --- probabilities + renormalize + coalesced store ---
  float pr[EPT];
  float ps = 0.f;
#pragma unroll
  for (int e = 0; e < EPT; ++e) {
    pr[e] = s[e].x * s[e].x + s[e].y * s[e].y;
    ps += pr[e];
  }
  float tot = block_reduce_sum(ps, red);
  bool okp = tot > 1e-10f;
  float invt = okp ? 1.0f / tot : 0.f;
  float o[EPT];
#pragma unroll
  for (int e = 0; e < EPT; ++e) o[e] = okp ? pr[e] * invt : (1.0f / DIM);
  float4* orow = (float4*)(out + b * (long)DIM) + tid * 2;
  orow[0] = make_float4(o[0], o[1], o[2], o[3]);
  orow[1] = make_float4(o[4], o[5], o[6], o[7]);
}

extern "C" void kernel_launch(void* const* d_in, const int* in_sizes, int n_in,
                              void* d_out, int out_size, void* d_ws, size_t ws_size,
                              hipStream_t stream) {
  const float* x = (const float*)d_in[0];
  const float* w = (const float*)d_in[1];
  float* out = (float*)d_out;
  const int B = in_sizes[0] / DIM;
  qsim_kernel<<<B, NT, 0, stream>>>(x, w, out);
}